// Round 1
// baseline (555.371 us; speedup 1.0000x reference)
//
#include <hip/hip_runtime.h>
#include <hip/hip_bf16.h>

// Problem dims (fixed)
#define Bq   4
#define Tq   2048
#define Cq   1024
#define Hq   16
#define HSq  64
#define DFFq 4096
#define Mq   (Bq*Tq)   // 8192 rows

typedef float f32x4  __attribute__((ext_vector_type(4)));
typedef short bf16x8 __attribute__((ext_vector_type(8)));   // 8 bf16 in 4 VGPRs

__device__ __forceinline__ float b2f(unsigned short u){ return __uint_as_float(((unsigned)u)<<16); }
__device__ __forceinline__ unsigned short f2b(float f){
  union { __hip_bfloat16 h; unsigned short u; } cv;
  cv.h = __float2bfloat16(f);
  return cv.u;
}
// fast pair-pack fp32->bf16x2 (round-half-up; inputs never NaN)
__device__ __forceinline__ unsigned pkbf(float a, float b){
  const unsigned ua = __float_as_uint(a) + 0x8000u;
  const unsigned ub = __float_as_uint(b) + 0x8000u;
  return (ua>>16) | (ub & 0xffff0000u);
}

// async global->LDS, 16B per lane. Per-lane lds ptr must equal
// wave-uniform base + lane*16 (m104/m108; validated R4/R5).
__device__ __forceinline__ void gld_lds16(const unsigned short* g, unsigned short* l){
  __builtin_amdgcn_global_load_lds(
      (const __attribute__((address_space(1))) void*)g,
      (__attribute__((address_space(3))) void*)l, 16, 0, 0);
}

// ---------------------------------------------------------------------------
// In-kernel dtype probe: wave-parallel scan of W1's first 256 u16.
// ---------------------------------------------------------------------------
__device__ __forceinline__ int probe_bf16(const unsigned short* w){
  const int lane = threadIdx.x & 63;
  ushort4 u = *(const ushort4*)(w + lane*4);
  int cnt = 0;
  {
    unsigned e;
    e=(u.x>>7)&0xFF; cnt += (e>=0x60 && e<=0x7E);
    e=(u.y>>7)&0xFF; cnt += (e>=0x60 && e<=0x7E);
    e=(u.z>>7)&0xFF; cnt += (e>=0x60 && e<=0x7E);
    e=(u.w>>7)&0xFF; cnt += (e>=0x60 && e<=0x7E);
  }
#pragma unroll
  for (int off=1; off<64; off<<=1) cnt += __shfl_xor(cnt, off, 64);
  return cnt >= 224;
}

// ---------------------------------------------------------------------------
// Convert the 10 parameter vectors to bf16 into ws (4096-elem slots):
// slots: bq bk bv bo | b1 | b2 g1 be1 g2 be2
// ---------------------------------------------------------------------------
__global__ __launch_bounds__(256) void cvtvec_k(
    const void* s0,const void* s1,const void* s2,const void* s3,const void* s4,
    const void* s5,const void* s6,const void* s7,const void* s8,const void* s9,
    const unsigned short* __restrict__ probew, unsigned short* __restrict__ dst)
{
  const int isbf = probe_bf16(probew);
  const int idx = blockIdx.x*256 + threadIdx.x;   // [0, 40960)
  const int seg = idx>>12, off = idx&4095;
  const void* s; int len;
  switch(seg){
    case 0: s=s0; len=1024; break;
    case 1: s=s1; len=1024; break;
    case 2: s=s2; len=1024; break;
    case 3: s=s3; len=1024; break;
    case 4: s=s4; len=4096; break;
    case 5: s=s5; len=1024; break;
    case 6: s=s6; len=1024; break;
    case 7: s=s7; len=1024; break;
    case 8: s=s8; len=1024; break;
    default: s=s9; len=1024; break;
  }
  if (off >= len) return;
  const float v = isbf ? b2f(((const unsigned short*)s)[off]) : ((const float*)s)[off];
  dst[idx] = f2b(v);
}

// ---------------------------------------------------------------------------
// LayerNorm: one block per row of C=1024. Input dtype self-probed.
// ---------------------------------------------------------------------------
__global__ __launch_bounds__(256) void ln_k(const void* __restrict__ xin,
    const unsigned short* __restrict__ g, const unsigned short* __restrict__ be,
    unsigned short* __restrict__ out, const unsigned short* __restrict__ probew)
{
  const int isbf = probe_bf16(probew);
  const int row = blockIdx.x;
  const int tid = threadIdx.x;
  float v[4];
  if (isbf){
    const unsigned short* xr = (const unsigned short*)xin + (size_t)row*Cq;
    ushort4 u = *(const ushort4*)(xr + tid*4);
    v[0]=b2f(u.x); v[1]=b2f(u.y); v[2]=b2f(u.z); v[3]=b2f(u.w);
  } else {
    const float* xr = (const float*)xin + (size_t)row*Cq;
    float4 u = *(const float4*)(xr + tid*4);
    v[0]=u.x; v[1]=u.y; v[2]=u.z; v[3]=u.w;
  }
  float s  = v[0]+v[1]+v[2]+v[3];
  float ss = v[0]*v[0]+v[1]*v[1]+v[2]*v[2]+v[3]*v[3];
#pragma unroll
  for (int off=32; off>0; off>>=1){
    s  += __shfl_down(s,  off, 64);
    ss += __shfl_down(ss, off, 64);
  }
  __shared__ float sa[4], sb[4];
  const int wave = tid>>6, lane = tid&63;
  if (lane==0){ sa[wave]=s; sb[wave]=ss; }
  __syncthreads();
  s  = sa[0]+sa[1]+sa[2]+sa[3];
  ss = sb[0]+sb[1]+sb[2]+sb[3];
  const float mu  = s  * (1.0f/Cq);
  const float var = ss * (1.0f/Cq) - mu*mu;
  const float rs  = rsqrtf(fmaxf(var, 0.0f) + 1e-5f);
  ushort4 o; unsigned short* op = (unsigned short*)&o;
#pragma unroll
  for (int i=0;i<4;i++){
    const int ci = tid*4+i;
    op[i] = f2b((v[i]-mu)*rs*b2f(g[ci]) + b2f(be[ci]));
  }
  *(ushort4*)(out + (size_t)row*Cq + tid*4) = o;
}

// ---------------------------------------------------------------------------
// Fused transpose of the four 1024x1024 attention weights.
// grid (16,16,4): z=0..2 -> WqkvT + z*1M elems; z=3 -> WoT.
// ---------------------------------------------------------------------------
__global__ __launch_bounds__(256) void wtrans4_k(
    const void* __restrict__ w0, const void* __restrict__ w1,
    const void* __restrict__ w2, const void* __restrict__ w3,
    unsigned short* __restrict__ Wqkv, unsigned short* __restrict__ WoT,
    const unsigned short* __restrict__ probew)
{
  const int isbf = probe_bf16(probew);
  const int z = blockIdx.z;
  const void* Win = (z==0)?w0 : (z==1)?w1 : (z==2)?w2 : w3;
  unsigned short* Wt = (z<3) ? (Wqkv + (size_t)z*1048576) : WoT;
  __shared__ __align__(16) unsigned short tile[64][72];
  const int kb = blockIdx.x, nb = blockIdx.y, tid = threadIdx.x;
#pragma unroll
  for (int i=0;i<2;i++){
    const int v = tid + i*256;
    const int kr = v>>3, nc = (v&7)*8;
    if (isbf){
      *(uint4*)&tile[kr][nc] =
        *(const uint4*)((const unsigned short*)Win + (size_t)(kb*64+kr)*1024 + nb*64 + nc);
    } else {
      const float* wp = (const float*)Win + (size_t)(kb*64+kr)*1024 + nb*64 + nc;
      float4 a = *(const float4*)wp, b = *(const float4*)(wp+4);
      alignas(16) unsigned short t[8] =
        {f2b(a.x),f2b(a.y),f2b(a.z),f2b(a.w),f2b(b.x),f2b(b.y),f2b(b.z),f2b(b.w)};
      *(uint4*)&tile[kr][nc] = *(const uint4*)t;
    }
  }
  __syncthreads();
#pragma unroll
  for (int i=0;i<2;i++){
    const int v = tid + i*256;
    const int nr = v>>3, kc = (v&7)*8;
    alignas(16) unsigned short tmp[8];
#pragma unroll
    for (int j=0;j<8;j++) tmp[j] = tile[kc+j][nr];
    *(uint4*)(Wt + (size_t)(nb*64+nr)*1024 + kb*64 + kc) = *(const uint4*)tmp;
  }
}

// ---------------------------------------------------------------------------
// Generic tiled transpose (for W1/W2). grid (Kd/64, Nd/64).
// ---------------------------------------------------------------------------
__global__ __launch_bounds__(256) void wtrans_k(const void* __restrict__ Win,
    unsigned short* __restrict__ Wt, const int Kd, const int Nd,
    const unsigned short* __restrict__ probew)
{
  const int isbf = probe_bf16(probew);
  __shared__ __align__(16) unsigned short tile[64][72];
  const int kb = blockIdx.x, nb = blockIdx.y, tid = threadIdx.x;
#pragma unroll
  for (int i=0;i<2;i++){
    const int v = tid + i*256;
    const int kr = v>>3, nc = (v&7)*8;
    if (isbf){
      *(uint4*)&tile[kr][nc] =
        *(const uint4*)((const unsigned short*)Win + (size_t)(kb*64+kr)*Nd + nb*64 + nc);
    } else {
      const float* wp = (const float*)Win + (size_t)(kb*64+kr)*Nd + nb*64 + nc;
      float4 a = *(const float4*)wp, b = *(const float4*)(wp+4);
      alignas(16) unsigned short t[8] =
        {f2b(a.x),f2b(a.y),f2b(a.z),f2b(a.w),f2b(b.x),f2b(b.y),f2b(b.z),f2b(b.w)};
      *(uint4*)&tile[kr][nc] = *(const uint4*)t;
    }
  }
  __syncthreads();
#pragma unroll
  for (int i=0;i<2;i++){
    const int v = tid + i*256;
    const int nr = v>>3, kc = (v&7)*8;
    alignas(16) unsigned short tmp[8];
#pragma unroll
    for (int j=0;j<8;j++) tmp[j] = tile[kc+j][nr];
    *(uint4*)(Wt + (size_t)(nb*64+nr)*Kd + kb*64 + kc) = *(const uint4*)tmp;
  }
}

// ---------------------------------------------------------------------------
// Pipelined GEMM: out[M][N] = A[M][K] @ Bt[N][K]^T + bias (+relu/resid).
// 256x128 tile, BK=64, 512 threads = 8 waves (4M x 2N), per-wave 64x64 out
// (4x4 mfma_f32_16x16x32_bf16 frags — same proven geometry as before).
// T3/T4: 3-deep LDS slot rotation (144 KiB), tile T+2 staged during tile T,
// boundary = s_waitcnt vmcnt(6) + raw s_barrier (ONE barrier per K-step,
// never drains to 0 mid-loop; only last tile waits vmcnt(0)).
// T5: s_setprio(1) around each 16-MFMA cluster (2 waves/SIMD role-split).
// Race-freedom: slot (T+2)%3 was freed at tile T-1's boundary barrier;
// all ds_reads of a tile complete (lgkmcnt before MFMA) before the wave
// reaches the next boundary barrier, which precedes any overwrite.
// ADD-swizzled LDS (physical colgrp pg holds logical (pg+row)&7): 0 bank
// conflicts measured on the predecessor.
// RESMODE: 0 none, 2 external resid (dtype probed).
// OUTMODE: 0 bf16 internal, 1 external dtype, 3 fused-QKV routing,
//          5 W2 split-K (fp32: atomicAdd; bf16: z==0 full-K).
// ---------------------------------------------------------------------------
template<int RELU, int RESMODE, int OUTMODE>
__global__ __launch_bounds__(512,2) void gemm256(
    const unsigned short* __restrict__ A,
    const unsigned short* __restrict__ Bt,
    const unsigned short* __restrict__ bias,
    const void* resid, void* outp,
    const int N, const int K, const int lda, const int ldb,
    const unsigned short* __restrict__ probew)
{
  int isbf = 1;
  if constexpr (OUTMODE==1 || OUTMODE==5 || RESMODE==2) isbf = probe_bf16(probew);

  int koff = 0;
  int nT = K >> 6;
  if constexpr (OUTMODE==5){
    if (isbf){
      if (blockIdx.z) return;
      nT = K >> 5;
    } else {
      koff = blockIdx.z * K;
    }
  }

  __shared__ __align__(16) unsigned short Al[3][256][64];   // 96 KiB
  __shared__ __align__(16) unsigned short Bl[3][128][64];   // 48 KiB

  const int tid  = threadIdx.x;
  const int lane = tid & 63, wave = tid >> 6;
  const int qd   = lane >> 4, c = lane & 15;
  const int m0   = blockIdx.x * 256, n0 = blockIdx.y * 128;
  const int wm   = (wave & 3) * 64;       // 4 M-waves x 64 rows
  const int wn   = (wave >> 2) * 64;      // 2 N-waves x 64 cols
  const int srow = tid >> 3;              // 0..63
  const int pg   = tid & 7;               // physical col group

  // stage K-tile t (6 gld_lds per thread: 4 A rows + 2 B rows) into slot
  auto STAGE = [&](int t, int slot){
    const int k0 = koff + t*64;
#pragma unroll
    for (int i=0;i<4;i++){
      const int row = i*64 + srow;
      const int lg  = (pg + row) & 7;
      gld_lds16(A  + (size_t)(m0+row)*lda + k0 + lg*8, &Al[slot][row][pg*8]);
    }
#pragma unroll
    for (int i=0;i<2;i++){
      const int row = i*64 + srow;
      const int lg  = (pg + row) & 7;
      gld_lds16(Bt + (size_t)(n0+row)*ldb + k0 + lg*8, &Bl[slot][row][pg*8]);
    }
  };

  const f32x4 zf = {0.f,0.f,0.f,0.f};
  f32x4 acc[4][4];
#pragma unroll
  for (int i=0;i<4;i++)
#pragma unroll
    for (int j=0;j<4;j++) acc[i][j] = zf;

  STAGE(0,0);
  if (nT > 1) STAGE(1,1);

  const int rg0 = ((qd     - c) & 7) * 8;   // ks=0 swizzled col group
  const int rg1 = ((4 + qd - c) & 7) * 8;   // ks=1

  int s = 0;
  for (int T=0; T<nT; ++T){
    // boundary: tile T's 6 loads must have landed; tile T+1's 6 stay in flight
    if (T+1 < nT) { asm volatile("s_waitcnt vmcnt(6)" ::: "memory"); }
    else          { asm volatile("s_waitcnt vmcnt(0)" ::: "memory"); }
    __builtin_amdgcn_s_barrier();
    asm volatile("" ::: "memory");

    const unsigned short (*As)[64] = Al[s];
    const unsigned short (*Bs)[64] = Bl[s];

    // phase 0: ks=0 — 8 ds_read_b128
    bf16x8 af0[4], bf0[4];
#pragma unroll
    for (int mt=0;mt<4;mt++) af0[mt] = *(const bf16x8*)&As[wm+mt*16+c][rg0];
#pragma unroll
    for (int nt=0;nt<4;nt++) bf0[nt] = *(const bf16x8*)&Bs[wn+nt*16+c][rg0];

    // prefetch tile T+2 into the slot freed at tile T-1's boundary
    if (T+2 < nT){
      const int ss = (s==0) ? 2 : s-1;    // (T+2) % 3
      STAGE(T+2, ss);
    }

    __builtin_amdgcn_s_setprio(1);
#pragma unroll
    for (int mt=0;mt<4;mt++)
#pragma unroll
      for (int nt=0;nt<4;nt++)
        acc[mt][nt] = __builtin_amdgcn_mfma_f32_16x16x32_bf16(af0[mt], bf0[nt], acc[mt][nt], 0,0,0);
    __builtin_amdgcn_s_setprio(0);

    // phase 1: ks=1 — 8 ds_read_b128
    bf16x8 af1[4], bf1[4];
#pragma unroll
    for (int mt=0;mt<4;mt++) af1[mt] = *(const bf16x8*)&As[wm+mt*16+c][rg1];
#pragma unroll
    for (int nt=0;nt<4;nt++) bf1[nt] = *(const bf16x8*)&Bs[wn+nt*16+c][rg1];

    __builtin_amdgcn_s_setprio(1);
#pragma unroll
    for (int mt=0;mt<4;mt++)
#pragma unroll
      for (int nt=0;nt<4;nt++)
        acc[mt][nt] = __builtin_amdgcn_mfma_f32_16x16x32_bf16(af1[mt], bf1[nt], acc[mt][nt], 0,0,0);
    __builtin_amdgcn_s_setprio(0);

    s = (s==2) ? 0 : s+1;
  }

  // epilogue: C/D layout col = lane&15, row = quad*4 + reg (m89/m91)
  float bv[4];
  if constexpr (OUTMODE==3){
    const int segn = (n0+wn) >> 10;
    const unsigned short* bseg = bias + segn*4096;
#pragma unroll
    for (int nt=0;nt<4;nt++) bv[nt] = b2f(bseg[(n0+wn+nt*16+c)&1023]);
  } else {
#pragma unroll
    for (int nt=0;nt<4;nt++) bv[nt] = b2f(bias[n0+wn+nt*16+c]);
  }

#pragma unroll
  for (int mt=0;mt<4;mt++){
#pragma unroll
    for (int r=0;r<4;r++){
      const int m = m0 + wm + mt*16 + qd*4 + r;
#pragma unroll
      for (int nt=0;nt<4;nt++){
        const int n = n0 + wn + nt*16 + c;
        float val = acc[mt][nt][r] + ((OUTMODE==5 && !isbf && blockIdx.z!=0) ? 0.0f : bv[nt]);
        if (RELU) val = fmaxf(val, 0.0f);
        if constexpr (RESMODE==2){
          const size_t idx = (size_t)m*N + n;
          val += isbf ? b2f(((const unsigned short*)resid)[idx])
                      : ((const float*)resid)[idx];
        }
        if constexpr (OUTMODE==3){
          const int segn = (n0+wn) >> 10;
          const int n1 = n & 1023;
          unsigned short* dst = (unsigned short*)outp + (size_t)segn*8388608;
          if (segn < 2){
            dst[(size_t)m*1024 + n1] = f2b(val);
          } else {
            const size_t vidx = ((size_t)((m>>11)*16 + (n1>>6))*64 + (n1&63))*Tq + (m&2047);
            dst[vidx] = f2b(val);
          }
        } else if constexpr (OUTMODE==5){
          const size_t idx = (size_t)m*N + n;
          if (!isbf){
            atomicAdd((float*)outp + idx, val);
          } else {
            unsigned short* o16 = (unsigned short*)outp;
            o16[idx] = f2b(val + b2f(o16[idx]));
          }
        } else if constexpr (OUTMODE==1){
          const size_t idx = (size_t)m*N + n;
          if (isbf) ((unsigned short*)outp)[idx] = f2b(val);
          else      ((float*)outp)[idx] = val;
        } else {
          ((unsigned short*)outp)[(size_t)m*N + n] = f2b(val);
        }
      }
    }
  }
}

// ---------------------------------------------------------------------------
// Causal flash attention, LDS-staged, UNNORMALIZED softmax (bounded-score:
// p = exp2(min(s*scl,80)), no online max/rescale — ratios identical, fp32
// cannot overflow: l <= 2048*2^80 ~ 2.5e27 << 3.4e38). Per-lane l partials,
// single cross-lane reduction at end. Fast packed bf16 P/O stores.
// grid = (B*H, T/128), 256 thr, 4 waves; heavy q-tiles dispatched first.
// ---------------------------------------------------------------------------
__global__ __launch_bounds__(256,3) void attn_k(const unsigned short* __restrict__ Qg,
    const unsigned short* __restrict__ Kg, const unsigned short* __restrict__ Vt,
    unsigned short* __restrict__ Y)
{
  const int bh = blockIdx.x;
  const int jq = (int)(gridDim.y - 1) - blockIdx.y;
  const int b = bh >> 4, h = bh & 15;
  const int tid = threadIdx.x, lane = tid & 63, wave = tid >> 6;
  const int qd = lane >> 4, c = lane & 15;
  const int q0  = jq * 128;
  const int wq0 = q0 + wave * 32;
  __shared__ __align__(16) unsigned short Kl[64*64];
  __shared__ __align__(16) unsigned short Vl[64*64];
  __shared__ __align__(16) unsigned short Pl[4][32][72];

  bf16x8 qf[2][2];
#pragma unroll
  for (int nt=0; nt<2; ++nt)
#pragma unroll
    for (int h2=0; h2<2; ++h2)
      qf[nt][h2] = *(const bf16x8*)(Qg + ((size_t)b*Tq + wq0 + nt*16 + c)*Cq
                                       + h*HSq + h2*32 + qd*8);

  const f32x4 zf = {0.f,0.f,0.f,0.f};
  const float NEG = -1.0e30f;
  f32x4 o[2][4];
  float lacc[2] = {0.f, 0.f};
#pragma unroll
  for (int nt=0;nt<2;nt++)
#pragma unroll
    for (int dt=0;dt<4;dt++) o[nt][dt]=zf;
  const float SCL = 0.125f * 1.44269504088896340736f;  // 1/sqrt(64)*log2(e)

  const int stg_r  = (lane>>3);
  const int stg_pg = lane & 7;

  // running staging pointers (advance by 64 keys per tile)
  const int r_row = (wave*2)*8 + stg_r;          // first of this wave's 2 rows
  const unsigned short* kp0 = Kg + ((size_t)b*Tq + r_row)*Cq + h*HSq + ((stg_pg + r_row)&7)*8;
  const unsigned short* kp1 = Kg + ((size_t)b*Tq + r_row+8)*Cq + h*HSq + ((stg_pg + r_row+8)&7)*8;
  const unsigned short* vp0 = Vt + ((size_t)bh*HSq + r_row)*Tq + ((stg_pg + r_row)&7)*8;
  const unsigned short* vp1 = Vt + ((size_t)bh*HSq + r_row+8)*Tq + ((stg_pg + r_row+8)&7)*8;
  unsigned short* kl0 = &Kl[(r_row  )*64 + stg_pg*8];
  unsigned short* kl1 = &Kl[(r_row+8)*64 + stg_pg*8];
  unsigned short* vl0 = &Vl[(r_row  )*64 + stg_pg*8];
  unsigned short* vl1 = &Vl[(r_row+8)*64 + stg_pg*8];

  const int nkt = 2*(jq+1);
  for (int kt=0; kt<nkt; ++kt){
    const int k0 = kt*64;
    gld_lds16(kp0, kl0);  gld_lds16(kp1, kl1);
    gld_lds16(vp0, vl0);  gld_lds16(vp1, vl1);
    kp0 += 64*Cq; kp1 += 64*Cq; vp0 += 64; vp1 += 64;
    __syncthreads();

    if (k0 <= wq0 + 31){
      bf16x8 kf[4][2], vf[4][2];
#pragma unroll
      for (int mt=0;mt<4;mt++)
#pragma unroll
        for (int h2=0;h2<2;h2++){
          kf[mt][h2] = *(const bf16x8*)&Kl[(mt*16+c)*64 + ((h2*4+qd-c)&7)*8];
          vf[mt][h2] = *(const bf16x8*)&Vl[(mt*16+c)*64 + ((h2*4+qd-c)&7)*8];
        }
      const int domask = (k0 + 63 > wq0) ? 1 : 0;
#pragma unroll
      for (int nt=0; nt<2; ++nt){
        const int query = wq0 + nt*16 + c;
        f32x4 s[4];
#pragma unroll
        for (int mt=0;mt<4;mt++){
          f32x4 sa = zf;
          sa = __builtin_amdgcn_mfma_f32_16x16x32_bf16(kf[mt][0], qf[nt][0], sa, 0,0,0);
          sa = __builtin_amdgcn_mfma_f32_16x16x32_bf16(kf[mt][1], qf[nt][1], sa, 0,0,0);
          s[mt] = sa;
        }
        // unnormalized softmax: p = exp2(min(s*SCL,80)); masked -> 0
        float p[4][4];
        float rs = 0.f;
#pragma unroll
        for (int mt=0;mt<4;mt++)
#pragma unroll
          for (int r=0;r<4;r++){
            float xv = fminf(s[mt][r]*SCL, 80.0f);
            if (domask && (k0 + mt*16 + qd*4 + r > query)) xv = NEG;
            const float pe = exp2f(xv);
            p[mt][r] = pe;
            rs += pe;
          }
        lacc[nt] += rs;
#pragma unroll
        for (int mt=0;mt<4;mt++){
          uint2 w2v;
          w2v.x = pkbf(p[mt][0], p[mt][1]);
          w2v.y = pkbf(p[mt][2], p[mt][3]);
          *(uint2*)&Pl[wave][nt*16+c][mt*16+qd*4] = w2v;
        }
        bf16x8 pf0 = *(const bf16x8*)&Pl[wave][nt*16+c][qd*8];
        bf16x8 pf1 = *(const bf16x8*)&Pl[wave][nt*16+c][32+qd*8];
#pragma unroll
        for (int dt=0;dt<4;dt++){
          o[nt][dt] = __builtin_amdgcn_mfma_f32_16x16x32_bf16(vf[dt][0], pf0, o[nt][dt], 0,0,0);
          o[nt][dt] = __builtin_amdgcn_mfma_f32_16x16x32_bf16(vf[dt][1], pf1, o[nt][dt], 0,0,0);
        }
      }
    }
    __syncthreads();
  }

  // final l reduction (additive across tiles -> reduce across qd groups once)
#pragma unroll
  for (int nt=0;nt<2;nt++){
    lacc[nt] += __shfl_xor(lacc[nt], 16, 64);
    lacc[nt] += __shfl_xor(lacc[nt], 32, 64);
  }
#pragma unroll
  for (int nt=0;nt<2;nt++){
    const float inv = 1.0f / lacc[nt];
#pragma unroll
    for (int dt=0;dt<4;dt++){
      uint2 w2v;
      w2v.x = pkbf(o[nt][dt][0]*inv, o[nt][dt][1]*inv);
      w2v.y = pkbf(o[nt][dt][2]*inv, o[nt][dt][3]*inv);
      *(uint2*)&Pl[wave][nt*16+c][dt*16+qd*4] = w2v;
    }
  }
#pragma unroll
  for (int pass=0; pass<4; ++pass){
    const int qrow = pass*8 + (lane>>3);
    const int dcol = (lane&7)*8;
    uint4 val = *(const uint4*)&Pl[wave][qrow][dcol];
    *(uint4*)(Y + ((size_t)b*Tq + wq0 + qrow)*Cq + h*HSq + dcol) = val;
  }
}

// ---------------------------------------------------------------------------
extern "C" void kernel_launch(void* const* d_in, const int* in_sizes, int n_in,
                              void* d_out, int out_size, void* d_ws, size_t ws_size,
                              hipStream_t stream)
{
  (void)in_sizes; (void)n_in; (void)out_size; (void)ws_size;
  const void* x   = d_in[0];
  const void* Wq  = d_in[1];
  const void* Wk  = d_in[3];
  const void* Wv  = d_in[5];
  const void* Wo  = d_in[7];
  const void* W1  = d_in[9];
  const void* W2  = d_in[11];
  const unsigned short* pw = (const unsigned short*)W1;   // dtype probe target

  // Workspace layout (~96.1 MiB peak, proven R3-R6):
  //  [0,8) W1T  [8,16) W2T  [16,22) WqkvT  [22,24) WoT
  //  [24,72) Qb@24 / Kb@40 / Vt@56   [16,80) ff1 overlay
  //  [80,96) hy    [96MB) vec params (80KB). x2 lives in d_out.
  char* ws = (char*)d_ws;
  const size_t MB = 1u<<20;
  unsigned short* W1T   = (unsigned short*)(ws + 0*MB);
  unsigned short* W2T   = (unsigned short*)(ws + 8*MB);
  unsigned short* WqkvT = (unsigned short*)(ws + 16*MB);
  unsigned short* WoT   = (unsigned short*)(ws + 22*MB);
  unsigned short* Qb    = (unsigned short*)(ws + 24*MB);
  unsigned short* Kb    = (unsigned short*)(ws + 40*MB);
  unsigned short* Vt    = (unsigned short*)(ws + 56*MB);
  unsigned short* ff1   = (unsigned short*)(ws + 16*MB);
  unsigned short* hy    = (unsigned short*)(ws + 80*MB);
  unsigned short* vec   = (unsigned short*)(ws + 96*MB);
  unsigned short* vbo = vec + 12288;
  unsigned short* vb1 = vec + 16384;  unsigned short* vb2 = vec + 20480;
  unsigned short* vg1 = vec + 24576;  unsigned short* vbe1= vec + 28672;
  unsigned short* vg2 = vec + 32768;  unsigned short* vbe2= vec + 36864;

  const dim3 blk(256,1,1);
  const dim3 blk512(512,1,1);

  cvtvec_k<<<dim3(160), blk, 0, stream>>>(d_in[2], d_in[4], d_in[6], d_in[8],
      d_in[10], d_in[12], d_in[13], d_in[14], d_in[15], d_in[16], pw, vec);

  wtrans4_k<<<dim3(16,16,4), blk, 0, stream>>>(Wq, Wk, Wv, Wo, WqkvT, WoT, pw);
  wtrans_k<<<dim3(16,64), blk, 0, stream>>>(W1, W1T, 1024, 4096, pw);
  wtrans_k<<<dim3(64,16), blk, 0, stream>>>(W2, W2T, 4096, 1024, pw);

  // ln1
  ln_k<<<dim3(Mq), blk, 0, stream>>>(x, vg1, vbe1, hy, pw);

  // fused QKV projection: N=3072, routes Q->Qb, K->Kb, V->Vt scatter
  gemm256<0,0,3><<<dim3(32,24), blk512, 0, stream>>>(hy, WqkvT, vec, nullptr, Qb,
      3072, 1024, 1024, 1024, pw);

  // causal attention: y -> hy
  attn_k<<<dim3(64,16), blk, 0, stream>>>(Qb, Kb, Vt, hy);

  // output projection + residual(x) -> x2 == d_out (external dtype)
  gemm256<0,2,1><<<dim3(32,8), blk512, 0, stream>>>(hy, WoT, vbo, x, d_out,
      1024, 1024, 1024, 1024, pw);

  // ln2
  ln_k<<<dim3(Mq), blk, 0, stream>>>(d_out, vg2, vbe2, hy, pw);

  // FFN
  gemm256<1,0,0><<<dim3(32,32), blk512, 0, stream>>>(hy, W1T, vb1, nullptr, ff1,
      4096, 1024, 1024, 1024, pw);
  gemm256<0,0,5><<<dim3(32,8,2), blk512, 0, stream>>>(ff1, W2T, vb2, nullptr, d_out,
      1024, 2048, 4096, 4096, pw);
}

// Round 2
// 542.334 us; speedup vs baseline: 1.0240x; 1.0240x over previous
//
#include <hip/hip_runtime.h>
#include <hip/hip_bf16.h>

// Problem dims (fixed)
#define Bq   4
#define Tq   2048
#define Cq   1024
#define Hq   16
#define HSq  64
#define DFFq 4096
#define Mq   (Bq*Tq)   // 8192 rows

typedef float f32x4  __attribute__((ext_vector_type(4)));
typedef short bf16x8 __attribute__((ext_vector_type(8)));   // 8 bf16 in 4 VGPRs

__device__ __forceinline__ float b2f(unsigned short u){ return __uint_as_float(((unsigned)u)<<16); }
__device__ __forceinline__ unsigned short f2b(float f){
  union { __hip_bfloat16 h; unsigned short u; } cv;
  cv.h = __float2bfloat16(f);
  return cv.u;
}
// fast pair-pack fp32->bf16x2 (round-half-up; inputs never NaN)
__device__ __forceinline__ unsigned pkbf(float a, float b){
  const unsigned ua = __float_as_uint(a) + 0x8000u;
  const unsigned ub = __float_as_uint(b) + 0x8000u;
  return (ua>>16) | (ub & 0xffff0000u);
}

// async global->LDS, 16B per lane. Per-lane lds ptr must equal
// wave-uniform base + lane*16 (m104/m108; validated R4/R5).
__device__ __forceinline__ void gld_lds16(const unsigned short* g, unsigned short* l){
  __builtin_amdgcn_global_load_lds(
      (const __attribute__((address_space(1))) void*)g,
      (__attribute__((address_space(3))) void*)l, 16, 0, 0);
}

// ---------------------------------------------------------------------------
// In-kernel dtype probe: wave-parallel scan of W1's first 256 u16.
// ---------------------------------------------------------------------------
__device__ __forceinline__ int probe_bf16(const unsigned short* w){
  const int lane = threadIdx.x & 63;
  ushort4 u = *(const ushort4*)(w + lane*4);
  int cnt = 0;
  {
    unsigned e;
    e=(u.x>>7)&0xFF; cnt += (e>=0x60 && e<=0x7E);
    e=(u.y>>7)&0xFF; cnt += (e>=0x60 && e<=0x7E);
    e=(u.z>>7)&0xFF; cnt += (e>=0x60 && e<=0x7E);
    e=(u.w>>7)&0xFF; cnt += (e>=0x60 && e<=0x7E);
  }
#pragma unroll
  for (int off=1; off<64; off<<=1) cnt += __shfl_xor(cnt, off, 64);
  return cnt >= 224;
}

// ---------------------------------------------------------------------------
// Convert the 10 parameter vectors to bf16 into ws (4096-elem slots):
// slots: bq bk bv bo | b1 | b2 g1 be1 g2 be2
// ---------------------------------------------------------------------------
__global__ __launch_bounds__(256) void cvtvec_k(
    const void* s0,const void* s1,const void* s2,const void* s3,const void* s4,
    const void* s5,const void* s6,const void* s7,const void* s8,const void* s9,
    const unsigned short* __restrict__ probew, unsigned short* __restrict__ dst)
{
  const int isbf = probe_bf16(probew);
  const int idx = blockIdx.x*256 + threadIdx.x;   // [0, 40960)
  const int seg = idx>>12, off = idx&4095;
  const void* s; int len;
  switch(seg){
    case 0: s=s0; len=1024; break;
    case 1: s=s1; len=1024; break;
    case 2: s=s2; len=1024; break;
    case 3: s=s3; len=1024; break;
    case 4: s=s4; len=4096; break;
    case 5: s=s5; len=1024; break;
    case 6: s=s6; len=1024; break;
    case 7: s=s7; len=1024; break;
    case 8: s=s8; len=1024; break;
    default: s=s9; len=1024; break;
  }
  if (off >= len) return;
  const float v = isbf ? b2f(((const unsigned short*)s)[off]) : ((const float*)s)[off];
  dst[idx] = f2b(v);
}

// ---------------------------------------------------------------------------
// LayerNorm: one block per row of C=1024. Input dtype self-probed.
// ---------------------------------------------------------------------------
__global__ __launch_bounds__(256) void ln_k(const void* __restrict__ xin,
    const unsigned short* __restrict__ g, const unsigned short* __restrict__ be,
    unsigned short* __restrict__ out, const unsigned short* __restrict__ probew)
{
  const int isbf = probe_bf16(probew);
  const int row = blockIdx.x;
  const int tid = threadIdx.x;
  float v[4];
  if (isbf){
    const unsigned short* xr = (const unsigned short*)xin + (size_t)row*Cq;
    ushort4 u = *(const ushort4*)(xr + tid*4);
    v[0]=b2f(u.x); v[1]=b2f(u.y); v[2]=b2f(u.z); v[3]=b2f(u.w);
  } else {
    const float* xr = (const float*)xin + (size_t)row*Cq;
    float4 u = *(const float4*)(xr + tid*4);
    v[0]=u.x; v[1]=u.y; v[2]=u.z; v[3]=u.w;
  }
  float s  = v[0]+v[1]+v[2]+v[3];
  float ss = v[0]*v[0]+v[1]*v[1]+v[2]*v[2]+v[3]*v[3];
#pragma unroll
  for (int off=32; off>0; off>>=1){
    s  += __shfl_down(s,  off, 64);
    ss += __shfl_down(ss, off, 64);
  }
  __shared__ float sa[4], sb[4];
  const int wave = tid>>6, lane = tid&63;
  if (lane==0){ sa[wave]=s; sb[wave]=ss; }
  __syncthreads();
  s  = sa[0]+sa[1]+sa[2]+sa[3];
  ss = sb[0]+sb[1]+sb[2]+sb[3];
  const float mu  = s  * (1.0f/Cq);
  const float var = ss * (1.0f/Cq) - mu*mu;
  const float rs  = rsqrtf(fmaxf(var, 0.0f) + 1e-5f);
  ushort4 o; unsigned short* op = (unsigned short*)&o;
#pragma unroll
  for (int i=0;i<4;i++){
    const int ci = tid*4+i;
    op[i] = f2b((v[i]-mu)*rs*b2f(g[ci]) + b2f(be[ci]));
  }
  *(ushort4*)(out + (size_t)row*Cq + tid*4) = o;
}

// ---------------------------------------------------------------------------
// Fused transpose of the four 1024x1024 attention weights.
// grid (16,16,4): z=0..2 -> WqkvT + z*1M elems; z=3 -> WoT.
// ---------------------------------------------------------------------------
__global__ __launch_bounds__(256) void wtrans4_k(
    const void* __restrict__ w0, const void* __restrict__ w1,
    const void* __restrict__ w2, const void* __restrict__ w3,
    unsigned short* __restrict__ Wqkv, unsigned short* __restrict__ WoT,
    const unsigned short* __restrict__ probew)
{
  const int isbf = probe_bf16(probew);
  const int z = blockIdx.z;
  const void* Win = (z==0)?w0 : (z==1)?w1 : (z==2)?w2 : w3;
  unsigned short* Wt = (z<3) ? (Wqkv + (size_t)z*1048576) : WoT;
  __shared__ __align__(16) unsigned short tile[64][72];
  const int kb = blockIdx.x, nb = blockIdx.y, tid = threadIdx.x;
#pragma unroll
  for (int i=0;i<2;i++){
    const int v = tid + i*256;
    const int kr = v>>3, nc = (v&7)*8;
    if (isbf){
      *(uint4*)&tile[kr][nc] =
        *(const uint4*)((const unsigned short*)Win + (size_t)(kb*64+kr)*1024 + nb*64 + nc);
    } else {
      const float* wp = (const float*)Win + (size_t)(kb*64+kr)*1024 + nb*64 + nc;
      float4 a = *(const float4*)wp, b = *(const float4*)(wp+4);
      alignas(16) unsigned short t[8] =
        {f2b(a.x),f2b(a.y),f2b(a.z),f2b(a.w),f2b(b.x),f2b(b.y),f2b(b.z),f2b(b.w)};
      *(uint4*)&tile[kr][nc] = *(const uint4*)t;
    }
  }
  __syncthreads();
#pragma unroll
  for (int i=0;i<2;i++){
    const int v = tid + i*256;
    const int nr = v>>3, kc = (v&7)*8;
    alignas(16) unsigned short tmp[8];
#pragma unroll
    for (int j=0;j<8;j++) tmp[j] = tile[kc+j][nr];
    *(uint4*)(Wt + (size_t)(nb*64+nr)*1024 + kb*64 + kc) = *(const uint4*)tmp;
  }
}

// ---------------------------------------------------------------------------
// Generic tiled transpose (for W1/W2). grid (Kd/64, Nd/64).
// ---------------------------------------------------------------------------
__global__ __launch_bounds__(256) void wtrans_k(const void* __restrict__ Win,
    unsigned short* __restrict__ Wt, const int Kd, const int Nd,
    const unsigned short* __restrict__ probew)
{
  const int isbf = probe_bf16(probew);
  __shared__ __align__(16) unsigned short tile[64][72];
  const int kb = blockIdx.x, nb = blockIdx.y, tid = threadIdx.x;
#pragma unroll
  for (int i=0;i<2;i++){
    const int v = tid + i*256;
    const int kr = v>>3, nc = (v&7)*8;
    if (isbf){
      *(uint4*)&tile[kr][nc] =
        *(const uint4*)((const unsigned short*)Win + (size_t)(kb*64+kr)*Nd + nb*64 + nc);
    } else {
      const float* wp = (const float*)Win + (size_t)(kb*64+kr)*Nd + nb*64 + nc;
      float4 a = *(const float4*)wp, b = *(const float4*)(wp+4);
      alignas(16) unsigned short t[8] =
        {f2b(a.x),f2b(a.y),f2b(a.z),f2b(a.w),f2b(b.x),f2b(b.y),f2b(b.z),f2b(b.w)};
      *(uint4*)&tile[kr][nc] = *(const uint4*)t;
    }
  }
  __syncthreads();
#pragma unroll
  for (int i=0;i<2;i++){
    const int v = tid + i*256;
    const int nr = v>>3, kc = (v&7)*8;
    alignas(16) unsigned short tmp[8];
#pragma unroll
    for (int j=0;j<8;j++) tmp[j] = tile[kc+j][nr];
    *(uint4*)(Wt + (size_t)(nb*64+nr)*Kd + kb*64 + kc) = *(const uint4*)tmp;
  }
}

// ---------------------------------------------------------------------------
// Phase-split pipelined GEMM (m201 8-phase-style schedule on 256x128 tiles).
// out[M][N] = A[M][K] @ Bt[N][K]^T + bias (+relu/resid).
// 256x128 tile, BK=64, 512 threads = 8 waves (4M x 2N), per-wave 64x64 out
// (4x4 mfma_f32_16x16x32_bf16 frags). 3-slot LDS rotation (144 KiB).
// Per K-tile: 2 phases, each {8x ds_read_b128 -> stage 3 gld_lds ->
// s_barrier -> setprio(1) -> 16 MFMA -> setprio(0) -> s_barrier}; ONE
// s_waitcnt vmcnt(6) per K-tile at the boundary (6 = tile T+2's just-issued
// loads; tile T+1's 6 stay in flight across the barrier). Dual barriers per
// phase create the producer/consumer wave stagger (T3) that makes counted
// vmcnt (T4) and setprio (T5) pay -- R1's single-phase variant measured
// -19% (m196's predicted regime).
// Race-freedom: stage targets slot (s+2)%3 = tile T-1's slot, issued only
// after T-1's end barrier (all its ds_reads done); tile T's arrival is
// guaranteed by the PREVIOUS boundary's vmcnt(6), which precedes tile T's
// first ds_read (asm memory clobber pins ordering). Requires nT >= 3.
// ADD-swizzled LDS (physical colgrp pg holds logical (pg+row)&7): 0 bank
// conflicts measured (R0/R1).
// RESMODE: 0 none, 2 external resid (dtype probed).
// OUTMODE: 0 bf16 internal, 1 external dtype, 3 fused-QKV routing,
//          5 W2 split-K (fp32: atomicAdd; bf16: z==0 full-K).
// ---------------------------------------------------------------------------
template<int RELU, int RESMODE, int OUTMODE>
__global__ __launch_bounds__(512,2) void gemm256(
    const unsigned short* __restrict__ A,
    const unsigned short* __restrict__ Bt,
    const unsigned short* __restrict__ bias,
    const void* resid, void* outp,
    const int N, const int K, const int lda, const int ldb,
    const unsigned short* __restrict__ probew)
{
  int isbf = 1;
  if constexpr (OUTMODE==1 || OUTMODE==5 || RESMODE==2) isbf = probe_bf16(probew);

  int koff = 0;
  int nT = K >> 6;
  if constexpr (OUTMODE==5){
    if (isbf){
      if (blockIdx.z) return;
      nT = K >> 5;
    } else {
      koff = blockIdx.z * K;
    }
  }

  __shared__ __align__(16) unsigned short Al[3][256][64];   // 96 KiB
  __shared__ __align__(16) unsigned short Bl[3][128][64];   // 48 KiB

  const int tid  = threadIdx.x;
  const int lane = tid & 63, wave = tid >> 6;
  const int qd   = lane >> 4, c = lane & 15;
  const int m0   = blockIdx.x * 256, n0 = blockIdx.y * 128;
  const int wm   = (wave & 3) * 64;       // 4 M-waves x 64 rows
  const int wn   = (wave >> 2) * 64;      // 2 N-waves x 64 cols
  const int srow = tid >> 3;              // 0..63
  const int pg   = tid & 7;               // physical col group

  // stage-group g (0 or 1) of K-tile t into slot: 3 gld_lds per thread
  // (g0: A rows 0-127 + B rows 0-63; g1: A rows 128-255 + B rows 64-127)
  auto STAGEg = [&](int t, int slot, int g){
    const int k0 = koff + t*64;
    const int ib = g*2;
#pragma unroll
    for (int i=0;i<2;i++){
      const int row = (ib+i)*64 + srow;
      const int lg  = (pg + row) & 7;
      gld_lds16(A + (size_t)(m0+row)*lda + k0 + lg*8, &Al[slot][row][pg*8]);
    }
    {
      const int row = g*64 + srow;
      const int lg  = (pg + row) & 7;
      gld_lds16(Bt + (size_t)(n0+row)*ldb + k0 + lg*8, &Bl[slot][row][pg*8]);
    }
  };

  const f32x4 zf = {0.f,0.f,0.f,0.f};
  f32x4 acc[4][4];
#pragma unroll
  for (int i=0;i<4;i++)
#pragma unroll
    for (int j=0;j<4;j++) acc[i][j] = zf;

  const int rg0 = ((qd     - c) & 7) * 8;   // ks=0 swizzled col group
  const int rg1 = ((4 + qd - c) & 7) * 8;   // ks=1

  // prologue: stage tiles 0 and 1 (12 loads); wait tile 0 (6 in flight ok)
  STAGEg(0,0,0); STAGEg(0,0,1);
  STAGEg(1,1,0); STAGEg(1,1,1);
  asm volatile("s_waitcnt vmcnt(6)" ::: "memory");
  __builtin_amdgcn_s_barrier();

  // K-tile body. wmode: 6 = steady boundary vmcnt(6)+barrier,
  // 0 = drain boundary vmcnt(0)+barrier, -1 = none (last tile).
  auto ktile = [&](int T, int s, bool stg, int wmode){
    const unsigned short (*As)[64] = Al[s];
    const unsigned short (*Bs)[64] = Bl[s];
    const int ss = (s >= 1) ? s-1 : 2;      // (s+2)%3
    bf16x8 af[4], bfr[4];

    // ---- phase 0 (ks=0) ----
#pragma unroll
    for (int mt=0;mt<4;mt++) af[mt]  = *(const bf16x8*)&As[wm+mt*16+c][rg0];
#pragma unroll
    for (int nt=0;nt<4;nt++) bfr[nt] = *(const bf16x8*)&Bs[wn+nt*16+c][rg0];
    if (stg) STAGEg(T+2, ss, 0);
    __builtin_amdgcn_s_barrier();
    __builtin_amdgcn_s_setprio(1);
#pragma unroll
    for (int mt=0;mt<4;mt++)
#pragma unroll
      for (int nt=0;nt<4;nt++)
        acc[mt][nt] = __builtin_amdgcn_mfma_f32_16x16x32_bf16(af[mt], bfr[nt], acc[mt][nt], 0,0,0);
    __builtin_amdgcn_s_setprio(0);
    __builtin_amdgcn_s_barrier();

    // ---- phase 1 (ks=1) ----
#pragma unroll
    for (int mt=0;mt<4;mt++) af[mt]  = *(const bf16x8*)&As[wm+mt*16+c][rg1];
#pragma unroll
    for (int nt=0;nt<4;nt++) bfr[nt] = *(const bf16x8*)&Bs[wn+nt*16+c][rg1];
    if (stg) STAGEg(T+2, ss, 1);
    __builtin_amdgcn_s_barrier();
    __builtin_amdgcn_s_setprio(1);
#pragma unroll
    for (int mt=0;mt<4;mt++)
#pragma unroll
      for (int nt=0;nt<4;nt++)
        acc[mt][nt] = __builtin_amdgcn_mfma_f32_16x16x32_bf16(af[mt], bfr[nt], acc[mt][nt], 0,0,0);
    __builtin_amdgcn_s_setprio(0);

    // ---- boundary ----
    if (wmode == 6)      asm volatile("s_waitcnt vmcnt(6)" ::: "memory");
    else if (wmode == 0) asm volatile("s_waitcnt vmcnt(0)" ::: "memory");
    if (wmode >= 0) __builtin_amdgcn_s_barrier();
  };

  int s = 0;
  for (int T=0; T<nT-2; ++T){
    ktile(T, s, true, 6);
    s = (s==2) ? 0 : s+1;
  }
  ktile(nT-2, s, false, 0);
  s = (s==2) ? 0 : s+1;
  ktile(nT-1, s, false, -1);

  // epilogue: C/D layout col = lane&15, row = quad*4 + reg (m89/m91)
  float bv[4];
  if constexpr (OUTMODE==3){
    const int segn = (n0+wn) >> 10;
    const unsigned short* bseg = bias + segn*4096;
#pragma unroll
    for (int nt=0;nt<4;nt++) bv[nt] = b2f(bseg[(n0+wn+nt*16+c)&1023]);
  } else {
#pragma unroll
    for (int nt=0;nt<4;nt++) bv[nt] = b2f(bias[n0+wn+nt*16+c]);
  }

#pragma unroll
  for (int mt=0;mt<4;mt++){
#pragma unroll
    for (int r=0;r<4;r++){
      const int m = m0 + wm + mt*16 + qd*4 + r;
#pragma unroll
      for (int nt=0;nt<4;nt++){
        const int n = n0 + wn + nt*16 + c;
        float val = acc[mt][nt][r] + ((OUTMODE==5 && !isbf && blockIdx.z!=0) ? 0.0f : bv[nt]);
        if (RELU) val = fmaxf(val, 0.0f);
        if constexpr (RESMODE==2){
          const size_t idx = (size_t)m*N + n;
          val += isbf ? b2f(((const unsigned short*)resid)[idx])
                      : ((const float*)resid)[idx];
        }
        if constexpr (OUTMODE==3){
          const int segn = (n0+wn) >> 10;
          const int n1 = n & 1023;
          unsigned short* dst = (unsigned short*)outp + (size_t)segn*8388608;
          if (segn < 2){
            dst[(size_t)m*1024 + n1] = f2b(val);
          } else {
            const size_t vidx = ((size_t)((m>>11)*16 + (n1>>6))*64 + (n1&63))*Tq + (m&2047);
            dst[vidx] = f2b(val);
          }
        } else if constexpr (OUTMODE==5){
          const size_t idx = (size_t)m*N + n;
          if (!isbf){
            atomicAdd((float*)outp + idx, val);
          } else {
            unsigned short* o16 = (unsigned short*)outp;
            o16[idx] = f2b(val + b2f(o16[idx]));
          }
        } else if constexpr (OUTMODE==1){
          const size_t idx = (size_t)m*N + n;
          if (isbf) ((unsigned short*)outp)[idx] = f2b(val);
          else      ((float*)outp)[idx] = val;
        } else {
          ((unsigned short*)outp)[(size_t)m*N + n] = f2b(val);
        }
      }
    }
  }
}

// ---------------------------------------------------------------------------
// Causal flash attention, LDS-staged, UNNORMALIZED softmax (bounded-score:
// p = exp2(min(s*scl,80)), no online max/rescale — ratios identical, fp32
// cannot overflow: l <= 2048*2^80 ~ 2.5e27 << 3.4e38). Per-lane l partials,
// single cross-lane reduction at end. Fast packed bf16 P/O stores.
// grid = (B*H, T/128), 256 thr, 4 waves; heavy q-tiles dispatched first.
// ---------------------------------------------------------------------------
__global__ __launch_bounds__(256,3) void attn_k(const unsigned short* __restrict__ Qg,
    const unsigned short* __restrict__ Kg, const unsigned short* __restrict__ Vt,
    unsigned short* __restrict__ Y)
{
  const int bh = blockIdx.x;
  const int jq = (int)(gridDim.y - 1) - blockIdx.y;
  const int b = bh >> 4, h = bh & 15;
  const int tid = threadIdx.x, lane = tid & 63, wave = tid >> 6;
  const int qd = lane >> 4, c = lane & 15;
  const int q0  = jq * 128;
  const int wq0 = q0 + wave * 32;
  __shared__ __align__(16) unsigned short Kl[64*64];
  __shared__ __align__(16) unsigned short Vl[64*64];
  __shared__ __align__(16) unsigned short Pl[4][32][72];

  bf16x8 qf[2][2];
#pragma unroll
  for (int nt=0; nt<2; ++nt)
#pragma unroll
    for (int h2=0; h2<2; ++h2)
      qf[nt][h2] = *(const bf16x8*)(Qg + ((size_t)b*Tq + wq0 + nt*16 + c)*Cq
                                       + h*HSq + h2*32 + qd*8);

  const f32x4 zf = {0.f,0.f,0.f,0.f};
  const float NEG = -1.0e30f;
  f32x4 o[2][4];
  float lacc[2] = {0.f, 0.f};
#pragma unroll
  for (int nt=0;nt<2;nt++)
#pragma unroll
    for (int dt=0;dt<4;dt++) o[nt][dt]=zf;
  const float SCL = 0.125f * 1.44269504088896340736f;  // 1/sqrt(64)*log2(e)

  const int stg_r  = (lane>>3);
  const int stg_pg = lane & 7;

  // running staging pointers (advance by 64 keys per tile)
  const int r_row = (wave*2)*8 + stg_r;          // first of this wave's 2 rows
  const unsigned short* kp0 = Kg + ((size_t)b*Tq + r_row)*Cq + h*HSq + ((stg_pg + r_row)&7)*8;
  const unsigned short* kp1 = Kg + ((size_t)b*Tq + r_row+8)*Cq + h*HSq + ((stg_pg + r_row+8)&7)*8;
  const unsigned short* vp0 = Vt + ((size_t)bh*HSq + r_row)*Tq + ((stg_pg + r_row)&7)*8;
  const unsigned short* vp1 = Vt + ((size_t)bh*HSq + r_row+8)*Tq + ((stg_pg + r_row+8)&7)*8;
  unsigned short* kl0 = &Kl[(r_row  )*64 + stg_pg*8];
  unsigned short* kl1 = &Kl[(r_row+8)*64 + stg_pg*8];
  unsigned short* vl0 = &Vl[(r_row  )*64 + stg_pg*8];
  unsigned short* vl1 = &Vl[(r_row+8)*64 + stg_pg*8];

  const int nkt = 2*(jq+1);
  for (int kt=0; kt<nkt; ++kt){
    const int k0 = kt*64;
    gld_lds16(kp0, kl0);  gld_lds16(kp1, kl1);
    gld_lds16(vp0, vl0);  gld_lds16(vp1, vl1);
    kp0 += 64*Cq; kp1 += 64*Cq; vp0 += 64; vp1 += 64;
    __syncthreads();

    if (k0 <= wq0 + 31){
      bf16x8 kf[4][2], vf[4][2];
#pragma unroll
      for (int mt=0;mt<4;mt++)
#pragma unroll
        for (int h2=0;h2<2;h2++){
          kf[mt][h2] = *(const bf16x8*)&Kl[(mt*16+c)*64 + ((h2*4+qd-c)&7)*8];
          vf[mt][h2] = *(const bf16x8*)&Vl[(mt*16+c)*64 + ((h2*4+qd-c)&7)*8];
        }
      const int domask = (k0 + 63 > wq0) ? 1 : 0;
#pragma unroll
      for (int nt=0; nt<2; ++nt){
        const int query = wq0 + nt*16 + c;
        f32x4 s[4];
#pragma unroll
        for (int mt=0;mt<4;mt++){
          f32x4 sa = zf;
          sa = __builtin_amdgcn_mfma_f32_16x16x32_bf16(kf[mt][0], qf[nt][0], sa, 0,0,0);
          sa = __builtin_amdgcn_mfma_f32_16x16x32_bf16(kf[mt][1], qf[nt][1], sa, 0,0,0);
          s[mt] = sa;
        }
        // unnormalized softmax: p = exp2(min(s*SCL,80)); masked -> 0
        float p[4][4];
        float rs = 0.f;
#pragma unroll
        for (int mt=0;mt<4;mt++)
#pragma unroll
          for (int r=0;r<4;r++){
            float xv = fminf(s[mt][r]*SCL, 80.0f);
            if (domask && (k0 + mt*16 + qd*4 + r > query)) xv = NEG;
            const float pe = exp2f(xv);
            p[mt][r] = pe;
            rs += pe;
          }
        lacc[nt] += rs;
#pragma unroll
        for (int mt=0;mt<4;mt++){
          uint2 w2v;
          w2v.x = pkbf(p[mt][0], p[mt][1]);
          w2v.y = pkbf(p[mt][2], p[mt][3]);
          *(uint2*)&Pl[wave][nt*16+c][mt*16+qd*4] = w2v;
        }
        bf16x8 pf0 = *(const bf16x8*)&Pl[wave][nt*16+c][qd*8];
        bf16x8 pf1 = *(const bf16x8*)&Pl[wave][nt*16+c][32+qd*8];
#pragma unroll
        for (int dt=0;dt<4;dt++){
          o[nt][dt] = __builtin_amdgcn_mfma_f32_16x16x32_bf16(vf[dt][0], pf0, o[nt][dt], 0,0,0);
          o[nt][dt] = __builtin_amdgcn_mfma_f32_16x16x32_bf16(vf[dt][1], pf1, o[nt][dt], 0,0,0);
        }
      }
    }
    __syncthreads();
  }

  // final l reduction (additive across tiles -> reduce across qd groups once)
#pragma unroll
  for (int nt=0;nt<2;nt++){
    lacc[nt] += __shfl_xor(lacc[nt], 16, 64);
    lacc[nt] += __shfl_xor(lacc[nt], 32, 64);
  }
#pragma unroll
  for (int nt=0;nt<2;nt++){
    const float inv = 1.0f / lacc[nt];
#pragma unroll
    for (int dt=0;dt<4;dt++){
      uint2 w2v;
      w2v.x = pkbf(o[nt][dt][0]*inv, o[nt][dt][1]*inv);
      w2v.y = pkbf(o[nt][dt][2]*inv, o[nt][dt][3]*inv);
      *(uint2*)&Pl[wave][nt*16+c][dt*16+qd*4] = w2v;
    }
  }
#pragma unroll
  for (int pass=0; pass<4; ++pass){
    const int qrow = pass*8 + (lane>>3);
    const int dcol = (lane&7)*8;
    uint4 val = *(const uint4*)&Pl[wave][qrow][dcol];
    *(uint4*)(Y + ((size_t)b*Tq + wq0 + qrow)*Cq + h*HSq + dcol) = val;
  }
}

// ---------------------------------------------------------------------------
extern "C" void kernel_launch(void* const* d_in, const int* in_sizes, int n_in,
                              void* d_out, int out_size, void* d_ws, size_t ws_size,
                              hipStream_t stream)
{
  (void)in_sizes; (void)n_in; (void)out_size; (void)ws_size;
  const void* x   = d_in[0];
  const void* Wq  = d_in[1];
  const void* Wk  = d_in[3];
  const void* Wv  = d_in[5];
  const void* Wo  = d_in[7];
  const void* W1  = d_in[9];
  const void* W2  = d_in[11];
  const unsigned short* pw = (const unsigned short*)W1;   // dtype probe target

  // Workspace layout (~96.1 MiB peak, proven R3-R6):
  //  [0,8) W1T  [8,16) W2T  [16,22) WqkvT  [22,24) WoT
  //  [24,72) Qb@24 / Kb@40 / Vt@56   [16,80) ff1 overlay
  //  [80,96) hy    [96MB) vec params (80KB). x2 lives in d_out.
  char* ws = (char*)d_ws;
  const size_t MB = 1u<<20;
  unsigned short* W1T   = (unsigned short*)(ws + 0*MB);
  unsigned short* W2T   = (unsigned short*)(ws + 8*MB);
  unsigned short* WqkvT = (unsigned short*)(ws + 16*MB);
  unsigned short* WoT   = (unsigned short*)(ws + 22*MB);
  unsigned short* Qb    = (unsigned short*)(ws + 24*MB);
  unsigned short* Kb    = (unsigned short*)(ws + 40*MB);
  unsigned short* Vt    = (unsigned short*)(ws + 56*MB);
  unsigned short* ff1   = (unsigned short*)(ws + 16*MB);
  unsigned short* hy    = (unsigned short*)(ws + 80*MB);
  unsigned short* vec   = (unsigned short*)(ws + 96*MB);
  unsigned short* vbo = vec + 12288;
  unsigned short* vb1 = vec + 16384;  unsigned short* vb2 = vec + 20480;
  unsigned short* vg1 = vec + 24576;  unsigned short* vbe1= vec + 28672;
  unsigned short* vg2 = vec + 32768;  unsigned short* vbe2= vec + 36864;

  const dim3 blk(256,1,1);
  const dim3 blk512(512,1,1);

  cvtvec_k<<<dim3(160), blk, 0, stream>>>(d_in[2], d_in[4], d_in[6], d_in[8],
      d_in[10], d_in[12], d_in[13], d_in[14], d_in[15], d_in[16], pw, vec);

  wtrans4_k<<<dim3(16,16,4), blk, 0, stream>>>(Wq, Wk, Wv, Wo, WqkvT, WoT, pw);
  wtrans_k<<<dim3(16,64), blk, 0, stream>>>(W1, W1T, 1024, 4096, pw);
  wtrans_k<<<dim3(64,16), blk, 0, stream>>>(W2, W2T, 4096, 1024, pw);

  // ln1
  ln_k<<<dim3(Mq), blk, 0, stream>>>(x, vg1, vbe1, hy, pw);

  // fused QKV projection: N=3072, routes Q->Qb, K->Kb, V->Vt scatter
  gemm256<0,0,3><<<dim3(32,24), blk512, 0, stream>>>(hy, WqkvT, vec, nullptr, Qb,
      3072, 1024, 1024, 1024, pw);

  // causal attention: y -> hy
  attn_k<<<dim3(64,16), blk, 0, stream>>>(Qb, Kb, Vt, hy);

  // output projection + residual(x) -> x2 == d_out (external dtype)
  gemm256<0,2,1><<<dim3(32,8), blk512, 0, stream>>>(hy, WoT, vbo, x, d_out,
      1024, 1024, 1024, 1024, pw);

  // ln2
  ln_k<<<dim3(Mq), blk, 0, stream>>>(d_out, vg2, vbe2, hy, pw);

  // FFN
  gemm256<1,0,0><<<dim3(32,32), blk512, 0, stream>>>(hy, W1T, vb1, nullptr, ff1,
      4096, 1024, 1024, 1024, pw);
  gemm256<0,0,5><<<dim3(32,8,2), blk512, 0, stream>>>(ff1, W2T, vb2, nullptr, d_out,
      1024, 2048, 4096, 4096, pw);
}

// Round 3
// 525.136 us; speedup vs baseline: 1.0576x; 1.0327x over previous
//
#include <hip/hip_runtime.h>
#include <hip/hip_bf16.h>

// Problem dims (fixed)
#define Bq   4
#define Tq   2048
#define Cq   1024
#define Hq   16
#define HSq  64
#define DFFq 4096
#define Mq   (Bq*Tq)   // 8192 rows

typedef float f32x4  __attribute__((ext_vector_type(4)));
typedef short bf16x8 __attribute__((ext_vector_type(8)));   // 8 bf16 in 4 VGPRs

__device__ __forceinline__ float b2f(unsigned short u){ return __uint_as_float(((unsigned)u)<<16); }
__device__ __forceinline__ unsigned short f2b(float f){
  union { __hip_bfloat16 h; unsigned short u; } cv;
  cv.h = __float2bfloat16(f);
  return cv.u;
}
// fast pair-pack fp32->bf16x2 (round-half-up; inputs never NaN)
__device__ __forceinline__ unsigned pkbf(float a, float b){
  const unsigned ua = __float_as_uint(a) + 0x8000u;
  const unsigned ub = __float_as_uint(b) + 0x8000u;
  return (ua>>16) | (ub & 0xffff0000u);
}

// async global->LDS, 16B per lane. Per-lane lds ptr must equal
// wave-uniform base + lane*16 (m104/m108; validated R4/R5).
__device__ __forceinline__ void gld_lds16(const unsigned short* g, unsigned short* l){
  __builtin_amdgcn_global_load_lds(
      (const __attribute__((address_space(1))) void*)g,
      (__attribute__((address_space(3))) void*)l, 16, 0, 0);
}

// ---------------------------------------------------------------------------
// In-kernel dtype probe: wave-parallel scan of W1's first 256 u16.
// ---------------------------------------------------------------------------
__device__ __forceinline__ int probe_bf16(const unsigned short* w){
  const int lane = threadIdx.x & 63;
  ushort4 u = *(const ushort4*)(w + lane*4);
  int cnt = 0;
  {
    unsigned e;
    e=(u.x>>7)&0xFF; cnt += (e>=0x60 && e<=0x7E);
    e=(u.y>>7)&0xFF; cnt += (e>=0x60 && e<=0x7E);
    e=(u.z>>7)&0xFF; cnt += (e>=0x60 && e<=0x7E);
    e=(u.w>>7)&0xFF; cnt += (e>=0x60 && e<=0x7E);
  }
#pragma unroll
  for (int off=1; off<64; off<<=1) cnt += __shfl_xor(cnt, off, 64);
  return cnt >= 224;
}

// ---------------------------------------------------------------------------
// Convert the 10 parameter vectors to bf16 into ws (4096-elem slots):
// slots: bq bk bv bo | b1 | b2 g1 be1 g2 be2
// ---------------------------------------------------------------------------
__global__ __launch_bounds__(256) void cvtvec_k(
    const void* s0,const void* s1,const void* s2,const void* s3,const void* s4,
    const void* s5,const void* s6,const void* s7,const void* s8,const void* s9,
    const unsigned short* __restrict__ probew, unsigned short* __restrict__ dst)
{
  const int isbf = probe_bf16(probew);
  const int idx = blockIdx.x*256 + threadIdx.x;   // [0, 40960)
  const int seg = idx>>12, off = idx&4095;
  const void* s; int len;
  switch(seg){
    case 0: s=s0; len=1024; break;
    case 1: s=s1; len=1024; break;
    case 2: s=s2; len=1024; break;
    case 3: s=s3; len=1024; break;
    case 4: s=s4; len=4096; break;
    case 5: s=s5; len=1024; break;
    case 6: s=s6; len=1024; break;
    case 7: s=s7; len=1024; break;
    case 8: s=s8; len=1024; break;
    default: s=s9; len=1024; break;
  }
  if (off >= len) return;
  const float v = isbf ? b2f(((const unsigned short*)s)[off]) : ((const float*)s)[off];
  dst[idx] = f2b(v);
}

// ---------------------------------------------------------------------------
// LayerNorm: one block per row of C=1024. Input dtype self-probed.
// ---------------------------------------------------------------------------
__global__ __launch_bounds__(256) void ln_k(const void* __restrict__ xin,
    const unsigned short* __restrict__ g, const unsigned short* __restrict__ be,
    unsigned short* __restrict__ out, const unsigned short* __restrict__ probew)
{
  const int isbf = probe_bf16(probew);
  const int row = blockIdx.x;
  const int tid = threadIdx.x;
  float v[4];
  if (isbf){
    const unsigned short* xr = (const unsigned short*)xin + (size_t)row*Cq;
    ushort4 u = *(const ushort4*)(xr + tid*4);
    v[0]=b2f(u.x); v[1]=b2f(u.y); v[2]=b2f(u.z); v[3]=b2f(u.w);
  } else {
    const float* xr = (const float*)xin + (size_t)row*Cq;
    float4 u = *(const float4*)(xr + tid*4);
    v[0]=u.x; v[1]=u.y; v[2]=u.z; v[3]=u.w;
  }
  float s  = v[0]+v[1]+v[2]+v[3];
  float ss = v[0]*v[0]+v[1]*v[1]+v[2]*v[2]+v[3]*v[3];
#pragma unroll
  for (int off=32; off>0; off>>=1){
    s  += __shfl_down(s,  off, 64);
    ss += __shfl_down(ss, off, 64);
  }
  __shared__ float sa[4], sb[4];
  const int wave = tid>>6, lane = tid&63;
  if (lane==0){ sa[wave]=s; sb[wave]=ss; }
  __syncthreads();
  s  = sa[0]+sa[1]+sa[2]+sa[3];
  ss = sb[0]+sb[1]+sb[2]+sb[3];
  const float mu  = s  * (1.0f/Cq);
  const float var = ss * (1.0f/Cq) - mu*mu;
  const float rs  = rsqrtf(fmaxf(var, 0.0f) + 1e-5f);
  ushort4 o; unsigned short* op = (unsigned short*)&o;
#pragma unroll
  for (int i=0;i<4;i++){
    const int ci = tid*4+i;
    op[i] = f2b((v[i]-mu)*rs*b2f(g[ci]) + b2f(be[ci]));
  }
  *(ushort4*)(out + (size_t)row*Cq + tid*4) = o;
}

// ---------------------------------------------------------------------------
// Fused transpose of the four 1024x1024 attention weights.
// grid (16,16,4): z=0..2 -> WqkvT + z*1M elems; z=3 -> WoT.
// ---------------------------------------------------------------------------
__global__ __launch_bounds__(256) void wtrans4_k(
    const void* __restrict__ w0, const void* __restrict__ w1,
    const void* __restrict__ w2, const void* __restrict__ w3,
    unsigned short* __restrict__ Wqkv, unsigned short* __restrict__ WoT,
    const unsigned short* __restrict__ probew)
{
  const int isbf = probe_bf16(probew);
  const int z = blockIdx.z;
  const void* Win = (z==0)?w0 : (z==1)?w1 : (z==2)?w2 : w3;
  unsigned short* Wt = (z<3) ? (Wqkv + (size_t)z*1048576) : WoT;
  __shared__ __align__(16) unsigned short tile[64][72];
  const int kb = blockIdx.x, nb = blockIdx.y, tid = threadIdx.x;
#pragma unroll
  for (int i=0;i<2;i++){
    const int v = tid + i*256;
    const int kr = v>>3, nc = (v&7)*8;
    if (isbf){
      *(uint4*)&tile[kr][nc] =
        *(const uint4*)((const unsigned short*)Win + (size_t)(kb*64+kr)*1024 + nb*64 + nc);
    } else {
      const float* wp = (const float*)Win + (size_t)(kb*64+kr)*1024 + nb*64 + nc;
      float4 a = *(const float4*)wp, b = *(const float4*)(wp+4);
      alignas(16) unsigned short t[8] =
        {f2b(a.x),f2b(a.y),f2b(a.z),f2b(a.w),f2b(b.x),f2b(b.y),f2b(b.z),f2b(b.w)};
      *(uint4*)&tile[kr][nc] = *(const uint4*)t;
    }
  }
  __syncthreads();
#pragma unroll
  for (int i=0;i<2;i++){
    const int v = tid + i*256;
    const int nr = v>>3, kc = (v&7)*8;
    alignas(16) unsigned short tmp[8];
#pragma unroll
    for (int j=0;j<8;j++) tmp[j] = tile[kc+j][nr];
    *(uint4*)(Wt + (size_t)(nb*64+nr)*1024 + kb*64 + kc) = *(const uint4*)tmp;
  }
}

// ---------------------------------------------------------------------------
// Generic tiled transpose (for W1/W2). grid (Kd/64, Nd/64).
// ---------------------------------------------------------------------------
__global__ __launch_bounds__(256) void wtrans_k(const void* __restrict__ Win,
    unsigned short* __restrict__ Wt, const int Kd, const int Nd,
    const unsigned short* __restrict__ probew)
{
  const int isbf = probe_bf16(probew);
  __shared__ __align__(16) unsigned short tile[64][72];
  const int kb = blockIdx.x, nb = blockIdx.y, tid = threadIdx.x;
#pragma unroll
  for (int i=0;i<2;i++){
    const int v = tid + i*256;
    const int kr = v>>3, nc = (v&7)*8;
    if (isbf){
      *(uint4*)&tile[kr][nc] =
        *(const uint4*)((const unsigned short*)Win + (size_t)(kb*64+kr)*Nd + nb*64 + nc);
    } else {
      const float* wp = (const float*)Win + (size_t)(kb*64+kr)*Nd + nb*64 + nc;
      float4 a = *(const float4*)wp, b = *(const float4*)(wp+4);
      alignas(16) unsigned short t[8] =
        {f2b(a.x),f2b(a.y),f2b(a.z),f2b(a.w),f2b(b.x),f2b(b.y),f2b(b.z),f2b(b.w)};
      *(uint4*)&tile[kr][nc] = *(const uint4*)t;
    }
  }
  __syncthreads();
#pragma unroll
  for (int i=0;i<2;i++){
    const int v = tid + i*256;
    const int nr = v>>3, kc = (v&7)*8;
    alignas(16) unsigned short tmp[8];
#pragma unroll
    for (int j=0;j<8;j++) tmp[j] = tile[kc+j][nr];
    *(uint4*)(Wt + (size_t)(nb*64+nr)*Kd + kb*64 + kc) = *(const uint4*)tmp;
  }
}

// ---------------------------------------------------------------------------
// GEMM: out[M][N] = A[M][K] @ Bt[N][K]^T + bias (+relu/resid).
// 128x128 tile, BK=64, 4 waves (2x2), 4x4 mfma_f32_16x16x32_bf16/wave.
// ADD-swizzled LDS tiles (2-way-max bank access, m136).
// PROVEN R0 structure (3 blocks/CU implicit overlap, m114). Two rounds of
// deep-pipeline variants (256x128 3-slot, phase-split dual-barrier) measured
// -16..-19% -- 1 block/CU kills the cross-block overlap and sub-256^2
// 8-phase is null (m232). Do not revisit without the exact m201 template.
// RESMODE: 0 none, 2 external resid (dtype probed).
// OUTMODE: 0 bf16 internal, 1 external dtype, 3 fused-QKV routing,
//          5 W2 split-K (fp32: atomicAdd; bf16: z==0 full-K).
// ---------------------------------------------------------------------------
template<int RELU, int RESMODE, int OUTMODE>
__global__ __launch_bounds__(256,2) void gemm_bt(
    const unsigned short* __restrict__ A,
    const unsigned short* __restrict__ Bt,
    const unsigned short* __restrict__ bias,
    const void* resid, void* outp,
    const int N, const int K, const int lda, const int ldb,
    const unsigned short* __restrict__ probew)
{
  int isbf = 1;
  if constexpr (OUTMODE==1 || OUTMODE==5 || RESMODE==2) isbf = probe_bf16(probew);

  int koff = 0;
  int kTiles = K >> 6;
  if constexpr (OUTMODE==5){
    if (isbf){
      if (blockIdx.z) return;
      kTiles = K >> 5;
    } else {
      koff = blockIdx.z * K;
    }
  }

  __shared__ __align__(16) unsigned short Al[128][64];
  __shared__ __align__(16) unsigned short Bl[128][64];
  const int tid  = threadIdx.x;
  const int lane = tid & 63, wave = tid >> 6;
  const int qd   = lane >> 4, c = lane & 15;
  const int m0   = blockIdx.x * 128, n0 = blockIdx.y * 128;
  const int wm   = (wave & 1) * 64, wn = (wave >> 1) * 64;
  const int srow = tid >> 3;               // 0..31
  const int pg   = tid & 7;                // physical col group

  const f32x4 zf = {0.f,0.f,0.f,0.f};
  f32x4 acc[4][4];
#pragma unroll
  for (int i=0;i<4;i++)
#pragma unroll
    for (int j=0;j<4;j++) acc[i][j] = zf;

  for (int kt=0; kt<kTiles; ++kt){
    const int k0 = koff + kt*64;
#pragma unroll
    for (int i=0;i<4;i++){
      const int row = i*32 + srow;
      const int lg  = (pg + row) & 7;
      gld_lds16(A  + (size_t)(m0+row)*lda + k0 + lg*8, &Al[row][pg*8]);
      gld_lds16(Bt + (size_t)(n0+row)*ldb + k0 + lg*8, &Bl[row][pg*8]);
    }
    __syncthreads();
#pragma unroll
    for (int ks=0; ks<2; ++ks){
      const int rg = ((ks*4+qd-c)&7)*8;
      bf16x8 af[4], bfr[4];
#pragma unroll
      for (int mt=0;mt<4;mt++) af[mt]  = *(const bf16x8*)&Al[wm+mt*16+c][rg];
#pragma unroll
      for (int nt=0;nt<4;nt++) bfr[nt] = *(const bf16x8*)&Bl[wn+nt*16+c][rg];
#pragma unroll
      for (int mt=0;mt<4;mt++)
#pragma unroll
        for (int nt=0;nt<4;nt++)
          acc[mt][nt] = __builtin_amdgcn_mfma_f32_16x16x32_bf16(af[mt], bfr[nt], acc[mt][nt], 0,0,0);
    }
    __syncthreads();
  }

  // epilogue: C/D layout col = lane&15, row = quad*4 + reg (m89/m91)
  float bv[4];
  if constexpr (OUTMODE==3){
    const int segn = (n0+wn) >> 10;
    const unsigned short* bseg = bias + segn*4096;
#pragma unroll
    for (int nt=0;nt<4;nt++) bv[nt] = b2f(bseg[(n0+wn+nt*16+c)&1023]);
  } else {
#pragma unroll
    for (int nt=0;nt<4;nt++) bv[nt] = b2f(bias[n0+wn+nt*16+c]);
  }

#pragma unroll
  for (int mt=0;mt<4;mt++){
#pragma unroll
    for (int r=0;r<4;r++){
      const int m = m0 + wm + mt*16 + qd*4 + r;
#pragma unroll
      for (int nt=0;nt<4;nt++){
        const int n = n0 + wn + nt*16 + c;
        float val = acc[mt][nt][r] + ((OUTMODE==5 && !isbf && blockIdx.z!=0) ? 0.0f : bv[nt]);
        if (RELU) val = fmaxf(val, 0.0f);
        if constexpr (RESMODE==2){
          const size_t idx = (size_t)m*N + n;
          val += isbf ? b2f(((const unsigned short*)resid)[idx])
                      : ((const float*)resid)[idx];
        }
        if constexpr (OUTMODE==3){
          const int segn = (n0+wn) >> 10;
          const int n1 = n & 1023;
          unsigned short* dst = (unsigned short*)outp + (size_t)segn*8388608;
          if (segn < 2){
            dst[(size_t)m*1024 + n1] = f2b(val);
          } else {
            const size_t vidx = ((size_t)((m>>11)*16 + (n1>>6))*64 + (n1&63))*Tq + (m&2047);
            dst[vidx] = f2b(val);
          }
        } else if constexpr (OUTMODE==5){
          const size_t idx = (size_t)m*N + n;
          if (!isbf){
            atomicAdd((float*)outp + idx, val);
          } else {
            unsigned short* o16 = (unsigned short*)outp;
            o16[idx] = f2b(val + b2f(o16[idx]));
          }
        } else if constexpr (OUTMODE==1){
          const size_t idx = (size_t)m*N + n;
          if (isbf) ((unsigned short*)outp)[idx] = f2b(val);
          else      ((float*)outp)[idx] = val;
        } else {
          ((unsigned short*)outp)[(size_t)m*N + n] = f2b(val);
        }
      }
    }
  }
}

// ---------------------------------------------------------------------------
// Causal flash attention, LDS-staged, UNNORMALIZED softmax (bounded-score:
// p = exp2(min(s*scl,80)), no online max/rescale — ratios identical, fp32
// cannot overflow: l <= 2048*2^80 ~ 2.5e27 << 3.4e38). Per-lane l partials,
// single cross-lane reduction at end. Fast packed bf16 P/O stores.
// grid = (B*H, T/128), 256 thr, 4 waves; heavy q-tiles dispatched first.
// R3: DOUBLE-BUFFERED KV prefetch (T14 / T3-minimum-2-phase, m214v27 +17%):
// per tile: barrier -> stage(kt+1 -> buf^1) -> compute(buf). ONE barrier per
// tile (was 2); HBM latency of the stage hides under this tile's QK/SM/PV.
// Race-safe: the barrier guarantees (a) every wave's own prior gld_lds
// drained (compiler emits vmcnt(0) before s_barrier) so buf is ready, and
// (b) all readers of buf^1's previous content are done. Pl is strictly
// per-wave (no barrier needed). LDS 50 KB -> still 3 blocks/CU.
// ---------------------------------------------------------------------------
__global__ __launch_bounds__(256,3) void attn_k(const unsigned short* __restrict__ Qg,
    const unsigned short* __restrict__ Kg, const unsigned short* __restrict__ Vt,
    unsigned short* __restrict__ Y)
{
  const int bh = blockIdx.x;
  const int jq = (int)(gridDim.y - 1) - blockIdx.y;
  const int b = bh >> 4, h = bh & 15;
  const int tid = threadIdx.x, lane = tid & 63, wave = tid >> 6;
  const int qd = lane >> 4, c = lane & 15;
  const int q0  = jq * 128;
  const int wq0 = q0 + wave * 32;
  __shared__ __align__(16) unsigned short Kl[2][64*64];
  __shared__ __align__(16) unsigned short Vl[2][64*64];
  __shared__ __align__(16) unsigned short Pl[4][32][72];

  bf16x8 qf[2][2];
#pragma unroll
  for (int nt=0; nt<2; ++nt)
#pragma unroll
    for (int h2=0; h2<2; ++h2)
      qf[nt][h2] = *(const bf16x8*)(Qg + ((size_t)b*Tq + wq0 + nt*16 + c)*Cq
                                       + h*HSq + h2*32 + qd*8);

  const f32x4 zf = {0.f,0.f,0.f,0.f};
  const float NEG = -1.0e30f;
  f32x4 o[2][4];
  float lacc[2] = {0.f, 0.f};
#pragma unroll
  for (int nt=0;nt<2;nt++)
#pragma unroll
    for (int dt=0;dt<4;dt++) o[nt][dt]=zf;
  const float SCL = 0.125f * 1.44269504088896340736f;  // 1/sqrt(64)*log2(e)

  const int stg_r  = (lane>>3);
  const int stg_pg = lane & 7;

  // staging geometry: 2 rows per lane-group per buffer (r_row, r_row+8).
  // ADD-swizzle: physical colgroup stg_pg holds logical (stg_pg+row)&7 —
  // identical to the read side's (h2*4+qd-c)&7 lookup. Per-lane LDS dest
  // = wave-uniform base + lane*16 (gld_lds requirement).
  const int r_row = wave*16 + stg_r;
  const int sw0 = ((stg_pg + r_row  )&7)*8;
  const int sw1 = ((stg_pg + r_row+8)&7)*8;
  const unsigned short* kbase0 = Kg + ((size_t)b*Tq + r_row  )*Cq + h*HSq + sw0;
  const unsigned short* kbase1 = Kg + ((size_t)b*Tq + r_row+8)*Cq + h*HSq + sw1;
  const unsigned short* vbase0 = Vt + ((size_t)bh*HSq + r_row  )*Tq + sw0;
  const unsigned short* vbase1 = Vt + ((size_t)bh*HSq + r_row+8)*Tq + sw1;

  auto stageKV = [&](int kt, int buf){
    const size_t koffK = (size_t)kt*64*Cq;   // +64 key-rows in K
    const int    koffV = kt*64;              // +64 key-cols in Vt
    gld_lds16(kbase0 + koffK, &Kl[buf][(r_row  )*64 + stg_pg*8]);
    gld_lds16(kbase1 + koffK, &Kl[buf][(r_row+8)*64 + stg_pg*8]);
    gld_lds16(vbase0 + koffV, &Vl[buf][(r_row  )*64 + stg_pg*8]);
    gld_lds16(vbase1 + koffV, &Vl[buf][(r_row+8)*64 + stg_pg*8]);
  };

  const int nkt = 2*(jq+1);
  stageKV(0, 0);
  int cur = 0;
  for (int kt=0; kt<nkt; ++kt){
    __syncthreads();                       // buf[cur] landed; buf[cur^1] free
    if (kt+1 < nkt) stageKV(kt+1, cur^1);  // prefetch hides under compute
    const int k0 = kt*64;

    if (k0 <= wq0 + 31){
      bf16x8 kf[4][2], vf[4][2];
#pragma unroll
      for (int mt=0;mt<4;mt++)
#pragma unroll
        for (int h2=0;h2<2;h2++){
          kf[mt][h2] = *(const bf16x8*)&Kl[cur][(mt*16+c)*64 + ((h2*4+qd-c)&7)*8];
          vf[mt][h2] = *(const bf16x8*)&Vl[cur][(mt*16+c)*64 + ((h2*4+qd-c)&7)*8];
        }
      const int domask = (k0 + 63 > wq0) ? 1 : 0;
#pragma unroll
      for (int nt=0; nt<2; ++nt){
        const int query = wq0 + nt*16 + c;
        f32x4 s[4];
#pragma unroll
        for (int mt=0;mt<4;mt++){
          f32x4 sa = zf;
          sa = __builtin_amdgcn_mfma_f32_16x16x32_bf16(kf[mt][0], qf[nt][0], sa, 0,0,0);
          sa = __builtin_amdgcn_mfma_f32_16x16x32_bf16(kf[mt][1], qf[nt][1], sa, 0,0,0);
          s[mt] = sa;
        }
        // unnormalized softmax: p = exp2(min(s*SCL,80)); masked -> 0
        float p[4][4];
        float rs = 0.f;
#pragma unroll
        for (int mt=0;mt<4;mt++)
#pragma unroll
          for (int r=0;r<4;r++){
            float xv = fminf(s[mt][r]*SCL, 80.0f);
            if (domask && (k0 + mt*16 + qd*4 + r > query)) xv = NEG;
            const float pe = exp2f(xv);
            p[mt][r] = pe;
            rs += pe;
          }
        lacc[nt] += rs;
#pragma unroll
        for (int mt=0;mt<4;mt++){
          uint2 w2v;
          w2v.x = pkbf(p[mt][0], p[mt][1]);
          w2v.y = pkbf(p[mt][2], p[mt][3]);
          *(uint2*)&Pl[wave][nt*16+c][mt*16+qd*4] = w2v;
        }
        bf16x8 pf0 = *(const bf16x8*)&Pl[wave][nt*16+c][qd*8];
        bf16x8 pf1 = *(const bf16x8*)&Pl[wave][nt*16+c][32+qd*8];
#pragma unroll
        for (int dt=0;dt<4;dt++){
          o[nt][dt] = __builtin_amdgcn_mfma_f32_16x16x32_bf16(vf[dt][0], pf0, o[nt][dt], 0,0,0);
          o[nt][dt] = __builtin_amdgcn_mfma_f32_16x16x32_bf16(vf[dt][1], pf1, o[nt][dt], 0,0,0);
        }
      }
    }
    cur ^= 1;
  }

  // final l reduction (additive across tiles -> reduce across qd groups once)
#pragma unroll
  for (int nt=0;nt<2;nt++){
    lacc[nt] += __shfl_xor(lacc[nt], 16, 64);
    lacc[nt] += __shfl_xor(lacc[nt], 32, 64);
  }
#pragma unroll
  for (int nt=0;nt<2;nt++){
    const float inv = 1.0f / lacc[nt];
#pragma unroll
    for (int dt=0;dt<4;dt++){
      uint2 w2v;
      w2v.x = pkbf(o[nt][dt][0]*inv, o[nt][dt][1]*inv);
      w2v.y = pkbf(o[nt][dt][2]*inv, o[nt][dt][3]*inv);
      *(uint2*)&Pl[wave][nt*16+c][dt*16+qd*4] = w2v;
    }
  }
#pragma unroll
  for (int pass=0; pass<4; ++pass){
    const int qrow = pass*8 + (lane>>3);
    const int dcol = (lane&7)*8;
    uint4 val = *(const uint4*)&Pl[wave][qrow][dcol];
    *(uint4*)(Y + ((size_t)b*Tq + wq0 + qrow)*Cq + h*HSq + dcol) = val;
  }
}

// ---------------------------------------------------------------------------
extern "C" void kernel_launch(void* const* d_in, const int* in_sizes, int n_in,
                              void* d_out, int out_size, void* d_ws, size_t ws_size,
                              hipStream_t stream)
{
  (void)in_sizes; (void)n_in; (void)out_size; (void)ws_size;
  const void* x   = d_in[0];
  const void* Wq  = d_in[1];
  const void* Wk  = d_in[3];
  const void* Wv  = d_in[5];
  const void* Wo  = d_in[7];
  const void* W1  = d_in[9];
  const void* W2  = d_in[11];
  const unsigned short* pw = (const unsigned short*)W1;   // dtype probe target

  // Workspace layout (~96.1 MiB peak, proven R3-R6):
  //  [0,8) W1T  [8,16) W2T  [16,22) WqkvT  [22,24) WoT
  //  [24,72) Qb@24 / Kb@40 / Vt@56   [16,80) ff1 overlay
  //  [80,96) hy    [96MB) vec params (80KB). x2 lives in d_out.
  char* ws = (char*)d_ws;
  const size_t MB = 1u<<20;
  unsigned short* W1T   = (unsigned short*)(ws + 0*MB);
  unsigned short* W2T   = (unsigned short*)(ws + 8*MB);
  unsigned short* WqkvT = (unsigned short*)(ws + 16*MB);
  unsigned short* WoT   = (unsigned short*)(ws + 22*MB);
  unsigned short* Qb    = (unsigned short*)(ws + 24*MB);
  unsigned short* Kb    = (unsigned short*)(ws + 40*MB);
  unsigned short* Vt    = (unsigned short*)(ws + 56*MB);
  unsigned short* ff1   = (unsigned short*)(ws + 16*MB);
  unsigned short* hy    = (unsigned short*)(ws + 80*MB);
  unsigned short* vec   = (unsigned short*)(ws + 96*MB);
  unsigned short* vbo = vec + 12288;
  unsigned short* vb1 = vec + 16384;  unsigned short* vb2 = vec + 20480;
  unsigned short* vg1 = vec + 24576;  unsigned short* vbe1= vec + 28672;
  unsigned short* vg2 = vec + 32768;  unsigned short* vbe2= vec + 36864;

  const dim3 blk(256,1,1);

  cvtvec_k<<<dim3(160), blk, 0, stream>>>(d_in[2], d_in[4], d_in[6], d_in[8],
      d_in[10], d_in[12], d_in[13], d_in[14], d_in[15], d_in[16], pw, vec);

  wtrans4_k<<<dim3(16,16,4), blk, 0, stream>>>(Wq, Wk, Wv, Wo, WqkvT, WoT, pw);
  wtrans_k<<<dim3(16,64), blk, 0, stream>>>(W1, W1T, 1024, 4096, pw);
  wtrans_k<<<dim3(64,16), blk, 0, stream>>>(W2, W2T, 4096, 1024, pw);

  // ln1
  ln_k<<<dim3(Mq), blk, 0, stream>>>(x, vg1, vbe1, hy, pw);

  // fused QKV projection: N=3072, routes Q->Qb, K->Kb, V->Vt scatter
  gemm_bt<0,0,3><<<dim3(64,24), blk, 0, stream>>>(hy, WqkvT, vec, nullptr, Qb,
      3072, 1024, 1024, 1024, pw);

  // causal attention: y -> hy
  attn_k<<<dim3(64,16), blk, 0, stream>>>(Qb, Kb, Vt, hy);

  // output projection + residual(x) -> x2 == d_out (external dtype)
  gemm_bt<0,2,1><<<dim3(64,8), blk, 0, stream>>>(hy, WoT, vbo, x, d_out,
      1024, 1024, 1024, 1024, pw);

  // ln2
  ln_k<<<dim3(Mq), blk, 0, stream>>>(d_out, vg2, vbe2, hy, pw);

  // FFN
  gemm_bt<1,0,0><<<dim3(64,32), blk, 0, stream>>>(hy, W1T, vb1, nullptr, ff1,
      4096, 1024, 1024, 1024, pw);
  gemm_bt<0,0,5><<<dim3(64,8,2), blk, 0, stream>>>(ff1, W2T, vb2, nullptr, d_out,
      1024, 2048, 4096, 4096, pw);
}